// Round 6
// baseline (324.449 us; speedup 1.0000x reference)
//
#include <hip/hip_runtime.h>
#include <hip/hip_bf16.h>

using bf16 = __hip_bfloat16;
typedef __attribute__((ext_vector_type(8))) short short8;   // 8 x bf16 MFMA operand
typedef __attribute__((ext_vector_type(4))) float floatx4;  // MFMA accumulator

#define AS1 __attribute__((address_space(1)))
#define AS3 __attribute__((address_space(3)))

__device__ __forceinline__ floatx4 mfma16(short8 a, short8 b, floatx4 c) {
  return __builtin_amdgcn_mfma_f32_16x16x32_bf16(a, b, c, 0, 0, 0);
}
// async global->LDS, 16B per lane; LDS dest = wave-uniform base + lane*16
__device__ __forceinline__ void gload16(const bf16* g, bf16* l) {
  __builtin_amdgcn_global_load_lds((const AS1 unsigned*)g, (AS3 unsigned*)l, 16, 0, 0);
}

// ------------- fused fp32 -> bf16 casts for all 5 inputs (one launch) -------
__global__ void cast_all_k(const float* __restrict__ x, const float* __restrict__ Wq,
                           const float* __restrict__ Wk, const float* __restrict__ Wv,
                           const float* __restrict__ Wo, bf16* __restrict__ xb,
                           bf16* __restrict__ wqkv, bf16* __restrict__ wo_b) {
  int blk = blockIdx.x;
  const float* src;
  bf16* dst;
  int off;
  if (blk < 8192)       { src = x;  dst = xb;                 off = blk; }
  else if (blk < 12288) { src = Wq; dst = wqkv;               off = blk - 8192; }
  else if (blk < 13312) { src = Wk; dst = wqkv + 2048 * 2048; off = blk - 12288; }
  else if (blk < 14336) { src = Wv; dst = wqkv + 2560 * 2048; off = blk - 13312; }
  else                  { src = Wo; dst = wo_b;               off = blk - 14336; }
  int i = (off * 256 + threadIdx.x) * 4;
  float4 v = *(const float4*)(src + i);
  bf16 t[4] = {__float2bfloat16(v.x), __float2bfloat16(v.y),
               __float2bfloat16(v.z), __float2bfloat16(v.w)};
  *(ushort4*)(dst + i) = *(const ushort4*)t;
}

// ------- GEMM C[M,N] = A[M,K] * B[N,K]^T, bf16 in, OutT out -------
template <typename OutT>
__global__ __launch_bounds__(256, 2)
void gemm_bt(const bf16* __restrict__ A, const bf16* __restrict__ B,
             OutT* __restrict__ C, int M, int N, int K) {
  __shared__ alignas(16) bf16 As[128 * 32];
  __shared__ alignas(16) bf16 Bs[128 * 32];
  const int tid = threadIdx.x;
  const int w = tid >> 6, lane = tid & 63, l16 = lane & 15, quad = lane >> 4;
  const int bm = blockIdx.x << 7, bn = blockIdx.y << 7;
  const int wm = (w & 1) << 6, wn = (w >> 1) << 6;

  const int r = tid >> 2, p = tid & 3;
  const int g0 = (p ^ ((r >> 1) & 3)) << 3;            // source group (elems)
  const int g1 = (p ^ (((r + 64) >> 1) & 3)) << 3;
  const bf16* Ag0 = A + (long)(bm + r) * K + g0;
  const bf16* Ag1 = A + (long)(bm + r + 64) * K + g1;
  const bf16* Bg0 = B + (long)(bn + r) * K + g0;
  const bf16* Bg1 = B + (long)(bn + r + 64) * K + g1;
  bf16* Asw = As + (w << 9);  // wave LDS base (64 lanes * 8 elems)
  bf16* Bsw = Bs + (w << 9);

  floatx4 acc[4][4];
#pragma unroll
  for (int i = 0; i < 4; ++i)
#pragma unroll
    for (int j = 0; j < 4; ++j) acc[i][j] = (floatx4)(0.0f);

  for (int k0 = 0; k0 < K; k0 += 32) {
    gload16(Ag0 + k0, Asw);
    gload16(Ag1 + k0, Asw + 2048);
    gload16(Bg0 + k0, Bsw);
    gload16(Bg1 + k0, Bsw + 2048);
    __syncthreads();
    short8 af[4], bfv[4];
#pragma unroll
    for (int mi = 0; mi < 4; ++mi) {
      int row = wm + (mi << 4) + l16;
      int pos = quad ^ ((row >> 1) & 3);
      af[mi] = *(const short8*)(As + row * 32 + pos * 8);
    }
#pragma unroll
    for (int ni = 0; ni < 4; ++ni) {
      int row = wn + (ni << 4) + l16;
      int pos = quad ^ ((row >> 1) & 3);
      bfv[ni] = *(const short8*)(Bs + row * 32 + pos * 8);
    }
#pragma unroll
    for (int mi = 0; mi < 4; ++mi)
#pragma unroll
      for (int ni = 0; ni < 4; ++ni)
        acc[mi][ni] = mfma16(af[mi], bfv[ni], acc[mi][ni]);
    __syncthreads();
  }

#pragma unroll
  for (int mi = 0; mi < 4; ++mi)
#pragma unroll
    for (int ni = 0; ni < 4; ++ni)
#pragma unroll
      for (int rr = 0; rr < 4; ++rr) {
        int row = bm + wm + (mi << 4) + (quad << 2) + rr;  // C/D: row=quad*4+reg
        int col = bn + wn + (ni << 4) + l16;               //      col=lane&15
        float v = acc[mi][ni][rr];
        if constexpr (sizeof(OutT) == 2)
          C[(long)row * N + col] = __float2bfloat16(v);
        else
          C[(long)row * N + col] = v;
      }
}

// ---------------- RoPE: qkv[4096][3072] -> Q[B,H,S,DH]*scale, K[B,KVH,S,DH] ----
// Q scale = 1/sqrt(128) * log2(e): attention exp(s) becomes exp2(s') directly.
__global__ void rope_k(const bf16* __restrict__ qkv, bf16* __restrict__ Q,
                       bf16* __restrict__ Kd) {
  int idx = blockIdx.x * 256 + threadIdx.x;  // 4096*20*64 threads, d-pair each
  int d = idx & 63;
  int rest = idx >> 6;
  int head = rest % 20;
  int token = rest / 20;
  int s = token & 2047;
  int b = token >> 11;
  const float C0 = 0.20762050593046439f;  // log2(10000)/64
  float i1 = (float)(d >> 1);
  float inv1 = exp2f(-i1 * C0);
  float inv2 = exp2f(-(i1 + 32.0f) * C0);
  float a1 = (float)s * inv1, a2 = (float)s * inv2;
  float s1, c1, s2, c2;
  __sincosf(a1, &s1, &c1);
  __sincosf(a2, &s2, &c2);
  if (head < 16) {
    const bf16* p = qkv + (long)token * 3072 + head * 128 + d;
    float xlo = __bfloat162float(p[0]), xhi = __bfloat162float(p[64]);
    const float sc = 0.08838834764831845f * 1.4426950408889634f;  // 1/sqrt(128)*log2e
    float olo = (xlo * c1 - xhi * s1) * sc;
    float ohi = (xhi * c2 + xlo * s2) * sc;
    bf16* q = Q + ((long)((b << 4) + head) * 2048 + s) * 128 + d;
    q[0] = __float2bfloat16(olo);
    q[64] = __float2bfloat16(ohi);
  } else {
    int kvh = head - 16;
    const bf16* p = qkv + (long)token * 3072 + 2048 + kvh * 128 + d;
    float xlo = __bfloat162float(p[0]), xhi = __bfloat162float(p[64]);
    float olo = xlo * c1 - xhi * s1;
    float ohi = xhi * c2 + xlo * s2;
    bf16* kk = Kd + ((long)((b << 2) + kvh) * 2048 + s) * 128 + d;
    kk[0] = __float2bfloat16(olo);
    kk[64] = __float2bfloat16(ohi);
  }
}

// ---------------- V transpose: qkv V cols -> Vt[B,KVH,DH,S] ----------------
__global__ void vtrans_k(const bf16* __restrict__ qkv, bf16* __restrict__ Vt) {
  __shared__ bf16 t[32][33];
  int x = threadIdx.x, y = threadIdx.y;
  int s0 = blockIdx.x << 5, d0 = blockIdx.y << 5, bkv = blockIdx.z;
  int b = bkv >> 2, kvh = bkv & 3;
  const bf16* src = qkv + (long)((b << 11) + s0) * 3072 + 2560 + kvh * 128 + d0;
#pragma unroll
  for (int yy = y; yy < 32; yy += 8) t[yy][x] = src[(long)yy * 3072 + x];
  __syncthreads();
  bf16* dst = Vt + (long)((bkv << 7) + d0) * 2048 + s0;
#pragma unroll
  for (int yy = y; yy < 32; yy += 8) dst[(long)yy * 2048 + x] = t[x][yy];
}

// -------- flash attention: BQ=128/path, 32 q/wave/path, dbuf staging --------
// mask: key k valid iff k <= q + 128. Block t (0..7): q-tiles A = t (light),
// B = 15-t (heavy), 128 queries each; wave w owns queries [w*32, w*32+31] of
// both paths as two 16-q fragments. 64-key tiles: nkA = 2t+4,
// nkB = min(34-2t, 32); straddle (window=128 spans 2 tiles): mask A at
// j in {2t+2, 2t+3}, B at {32-2t, 33-2t}. Each kf/vf LDS read feeds 4 MFMAs
// (2 q-frags x 2 paths) -> ~0.57x LDS read instrs per unit work vs 16q/wave.
// S^T = K*Q^T; P = exp2(s) (scores pre-scaled by log2e/sqrt(128), no max-sub);
// l deferred to one end reduction.
__global__ __launch_bounds__(256, 1)
void attn_k(const bf16* __restrict__ Q, const bf16* __restrict__ K,
            const bf16* __restrict__ V, bf16* __restrict__ O) {
  __shared__ alignas(16) bf16 lk[2][64 * 128];   // [key][d]   16KB x2
  __shared__ alignas(16) bf16 lv[2][128 * 64];   // [d][key]   16KB x2
  __shared__ alignas(16) bf16 lpA[4 * 32 * 64];  // P per wave 32q x 64k, 16KB
  __shared__ alignas(16) bf16 lpB[4 * 32 * 64];  // 16KB
  const int tid = threadIdx.x, w = tid >> 6, lane = tid & 63;
  const int l16 = lane & 15, quad = lane >> 4;
  const int t = blockIdx.x;                      // 0..7
  const int qa0 = t << 7, qb0 = (15 - t) << 7;
  const int nkA = 2 * t + 4;
  int nkBt = 34 - 2 * t;
  const int nkB = nkBt < 32 ? nkBt : 32;
  const int jmA0 = 2 * t + 2, jmB0 = 32 - 2 * t; // straddle tile bases
  const int bh = blockIdx.y, b = bh >> 4, h = bh & 15, kvh = h >> 2;
  const bf16* Qp = Q + (long)bh * 2048 * 128;
  const bf16* Kp = K + (long)((b << 2) + kvh) * 2048 * 128;
  const bf16* Vp = V + (long)((b << 2) + kvh) * 128 * 2048;
  const int wq = w << 5;

  short8 qfA[2][4], qfB[2][4];  // [qfrag][kc] B-frags: n=query, k=quad*8..
#pragma unroll
  for (int f = 0; f < 2; ++f)
#pragma unroll
    for (int kc = 0; kc < 4; ++kc) {
      qfA[f][kc] = *(const short8*)(Qp + (long)(qa0 + wq + (f << 4) + l16) * 128 + kc * 32 + quad * 8);
      qfB[f][kc] = *(const short8*)(Qp + (long)(qb0 + wq + (f << 4) + l16) * 128 + kc * 32 + quad * 8);
    }

  floatx4 oA[8][2], oB[8][2];  // [d-tile][qfrag]
#pragma unroll
  for (int i = 0; i < 8; ++i)
#pragma unroll
    for (int f = 0; f < 2; ++f) { oA[i][f] = (floatx4)(0.0f); oB[i][f] = (floatx4)(0.0f); }
  float lA[2] = {0.0f, 0.0f}, lB[2] = {0.0f, 0.0f};  // per-lane l (query f*16+l16)

  bf16* pwA = lpA + (w << 11);  // 32 q x 64 k per wave
  bf16* pwB = lpB + (w << 11);
  const int sw = l16 & 7;       // P swizzle (query low-3)

  // stage 64-key K/V tile j into buffer bufi
  auto stage = [&](int j, int bufi) {
    const int k0 = j << 6;
    bf16* lkb = &lk[bufi][0];
    bf16* lvb = &lv[bufi][0];
#pragma unroll
    for (int i = 0; i < 4; ++i) {  // K [64][128]
      int c = i * 256 + tid;
      int row = c >> 4, pos = c & 15;
      int grp = (pos & 8) | ((pos & 7) ^ (row & 7));
      gload16(Kp + (long)(k0 + row) * 128 + grp * 8, lkb + (i * 256 + (w << 6)) * 8);
    }
#pragma unroll
    for (int i = 0; i < 4; ++i) {  // V [128 d][64 k]
      int c = i * 256 + tid;
      int row = c >> 3, grp = (c & 7) ^ (row & 7);
      gload16(Vp + (long)row * 2048 + k0 + grp * 8, lvb + (i * 256 + (w << 6)) * 8);
    }
  };

  auto tile = [&](auto bothc, int k0, bool maskA, bool maskB, int bufi) {
    constexpr bool BOTH = decltype(bothc)::value;
    const bf16* lkb = &lk[bufi][0];
    const bf16* lvb = &lv[bufi][0];
    floatx4 sA[4][2], sB[4][2];   // [key-tile][qfrag]
#pragma unroll
    for (int kt = 0; kt < 4; ++kt)
#pragma unroll
      for (int f = 0; f < 2; ++f) {
        sB[kt][f] = (floatx4)(0.0f);
        if constexpr (BOTH) sA[kt][f] = (floatx4)(0.0f);
      }
    // S^T = K*Q^T: each kf feeds 2 qfrags x 2 paths
#pragma unroll
    for (int kc = 0; kc < 4; ++kc) {
#pragma unroll
      for (int kt = 0; kt < 4; ++kt) {
        int row = (kt << 4) + l16;
        int g = (kc << 2) + quad;
        int pos = (g & 8) | ((g & 7) ^ (row & 7));
        short8 kf = *(const short8*)(lkb + row * 128 + pos * 8);
#pragma unroll
        for (int f = 0; f < 2; ++f) {
          sB[kt][f] = mfma16(kf, qfB[f][kc], sB[kt][f]);
          if constexpr (BOTH) sA[kt][f] = mfma16(kf, qfA[f][kc], sA[kt][f]);
        }
      }
    }
    // mask: S^T (kt,f,rr): key = k0+kt*16+quad*4+rr, query = qX0+wq+f*16+l16
    if (maskB) {
#pragma unroll
      for (int f = 0; f < 2; ++f) {
        int qg = qb0 + wq + (f << 4) + l16 + 128;
#pragma unroll
        for (int kt = 0; kt < 4; ++kt)
#pragma unroll
          for (int rr = 0; rr < 4; ++rr) {
            int kg = k0 + (kt << 4) + (quad << 2) + rr;
            if (kg > qg) sB[kt][f][rr] = -1e30f;
          }
      }
    }
    if constexpr (BOTH) {
      if (maskA) {
#pragma unroll
        for (int f = 0; f < 2; ++f) {
          int qg = qa0 + wq + (f << 4) + l16 + 128;
#pragma unroll
          for (int kt = 0; kt < 4; ++kt)
#pragma unroll
            for (int rr = 0; rr < 4; ++rr) {
              int kg = k0 + (kt << 4) + (quad << 2) + rr;
              if (kg > qg) sA[kt][f][rr] = -1e30f;
            }
        }
      }
    }
    // exp2 + packed b64 P-store (4 consecutive keys of one query per lane)
#pragma unroll
    for (int f = 0; f < 2; ++f) {
      int qrow = ((f << 4) + l16) << 6;
#pragma unroll
      for (int kt = 0; kt < 4; ++kt) {
        int g = (kt << 1) + (quad >> 1);
        int sl = (((g ^ sw) << 1) | (quad & 1)) << 2;  // elem offset
        {
          float p0 = exp2f(sB[kt][f][0]), p1 = exp2f(sB[kt][f][1]);
          float p2 = exp2f(sB[kt][f][2]), p3 = exp2f(sB[kt][f][3]);
          lB[f] += (p0 + p1) + (p2 + p3);
          bf16 tb[4] = {__float2bfloat16(p0), __float2bfloat16(p1),
                        __float2bfloat16(p2), __float2bfloat16(p3)};
          *(ushort4*)(pwB + qrow + sl) = *(const ushort4*)tb;
        }
        if constexpr (BOTH) {
          float p0 = exp2f(sA[kt][f][0]), p1 = exp2f(sA[kt][f][1]);
          float p2 = exp2f(sA[kt][f][2]), p3 = exp2f(sA[kt][f][3]);
          lA[f] += (p0 + p1) + (p2 + p3);
          bf16 ta[4] = {__float2bfloat16(p0), __float2bfloat16(p1),
                        __float2bfloat16(p2), __float2bfloat16(p3)};
          *(ushort4*)(pwA + qrow + sl) = *(const ushort4*)ta;
        }
      }
    }
    // PV: each vf feeds 2 qfrags x 2 paths
#pragma unroll
    for (int kcl = 0; kcl < 2; ++kcl) {
      int pp = (((kcl << 2) + quad) ^ sw) << 3;
      short8 pfB[2], pfA[2];
#pragma unroll
      for (int f = 0; f < 2; ++f) {
        pfB[f] = *(const short8*)(pwB + (((f << 4) + l16) << 6) + pp);
        if constexpr (BOTH) pfA[f] = *(const short8*)(pwA + (((f << 4) + l16) << 6) + pp);
      }
      int g = (kcl << 2) + quad;
#pragma unroll
      for (int nd = 0; nd < 8; ++nd) {
        int vrow = (nd << 4) + l16;
        int vpos = g ^ (vrow & 7);
        short8 vf = *(const short8*)(lvb + vrow * 64 + (vpos << 3));
#pragma unroll
        for (int f = 0; f < 2; ++f) {
          oB[nd][f] = mfma16(pfB[f], vf, oB[nd][f]);
          if constexpr (BOTH) oA[nd][f] = mfma16(pfA[f], vf, oA[nd][f]);
        }
      }
    }
  };

  stage(0, 0);
  __syncthreads();  // vmcnt(0) drain -> buf0 ready
  for (int j = 0; j < nkB; ++j) {
    if (j + 1 < nkB) stage(j + 1, (j + 1) & 1);  // prefetch overlaps compute
    const int k0 = j << 6;
    bool mA = (j == jmA0) | (j == jmA0 + 1);
    bool mB = (j == jmB0) | (j == jmB0 + 1);
    if (j < nkA)
      tile(std::integral_constant<bool, true>{}, k0, mA, mB, j & 1);
    else
      tile(std::integral_constant<bool, false>{}, k0, false, mB, j & 1);
    __syncthreads();  // drains prefetch (had full compute phase in flight)
  }

  // l: sum quads (lanes sharing l16), invert, redistribute to (quad,rr) rows
#pragma unroll
  for (int f = 0; f < 2; ++f) {
    lA[f] += __shfl_xor(lA[f], 16, 64); lA[f] += __shfl_xor(lA[f], 32, 64);
    lB[f] += __shfl_xor(lB[f], 16, 64); lB[f] += __shfl_xor(lB[f], 32, 64);
  }
  float rlA[2][4], rlB[2][4];
#pragma unroll
  for (int f = 0; f < 2; ++f) {
    float liA = 1.0f / lA[f], liB = 1.0f / lB[f];
#pragma unroll
    for (int rr = 0; rr < 4; ++rr) {
      int src = (quad << 2) + rr;
      rlA[f][rr] = __shfl(liA, src, 64);
      rlB[f][rr] = __shfl(liB, src, 64);
    }
  }

  bf16* OpA = O + ((long)(b << 11) + qa0 + wq) * 2048 + (h << 7);
  bf16* OpB = O + ((long)(b << 11) + qb0 + wq) * 2048 + (h << 7);
#pragma unroll
  for (int f = 0; f < 2; ++f)
#pragma unroll
    for (int nd = 0; nd < 8; ++nd)
#pragma unroll
      for (int rr = 0; rr < 4; ++rr) {
        int row = (f << 4) + (quad << 2) + rr;
        int col = (nd << 4) + l16;
        OpA[(long)row * 2048 + col] = __float2bfloat16(oA[nd][f][rr] * rlA[f][rr]);
        OpB[(long)row * 2048 + col] = __float2bfloat16(oB[nd][f][rr] * rlB[f][rr]);
      }
}

extern "C" void kernel_launch(void* const* d_in, const int* in_sizes, int n_in,
                              void* d_out, int out_size, void* d_ws, size_t ws_size,
                              hipStream_t stream) {
  (void)in_sizes; (void)n_in; (void)out_size; (void)ws_size;
  const float* x  = (const float*)d_in[0];
  const float* Wq = (const float*)d_in[1];
  const float* Wk = (const float*)d_in[2];
  const float* Wv = (const float*)d_in[3];
  const float* Wo = (const float*)d_in[4];
  char* ws = (char*)d_ws;
  // ws layout (bytes): xb 16.7M | wqkv 12.6M | wo_b 8.4M | qkv 25.2M | Q 16.8M | K 4.2M | Vt 4.2M
  bf16* xb   = (bf16*)(ws);                 // also reused as Ob after gemm1
  bf16* wqkv = (bf16*)(ws + 16777216);
  bf16* wo_b = (bf16*)(ws + 29360128);
  bf16* qkv  = (bf16*)(ws + 37748736);
  bf16* Qr   = (bf16*)(ws + 62914560);
  bf16* Kr   = (bf16*)(ws + 79691776);
  bf16* Vt   = (bf16*)(ws + 83886080);
  bf16* Ob   = xb;  // x dead after QKV GEMM
  float* out = (float*)d_out;

  cast_all_k<<<18432, 256, 0, stream>>>(x, Wq, Wk, Wv, Wo, xb, wqkv, wo_b);

  gemm_bt<bf16><<<dim3(32, 24), 256, 0, stream>>>(xb, wqkv, qkv, 4096, 3072, 2048);
  rope_k<<<20480, 256, 0, stream>>>(qkv, Qr, Kr);
  vtrans_k<<<dim3(64, 4, 8), dim3(32, 8), 0, stream>>>(qkv, Vt);
  attn_k<<<dim3(8, 32), 256, 0, stream>>>(Qr, Kr, Vt, Ob);
  gemm_bt<float><<<dim3(32, 16), 256, 0, stream>>>(Ob, wo_b, out, 4096, 2048, 2048);
}

// Round 7
// 302.413 us; speedup vs baseline: 1.0729x; 1.0729x over previous
//
#include <hip/hip_runtime.h>
#include <hip/hip_bf16.h>

using bf16 = __hip_bfloat16;
typedef __attribute__((ext_vector_type(8))) short short8;     // 8 x bf16 MFMA operand
typedef __attribute__((ext_vector_type(4))) float floatx4;    // 16x16 accumulator
typedef __attribute__((ext_vector_type(16))) float floatx16;  // 32x32 accumulator

#define AS1 __attribute__((address_space(1)))
#define AS3 __attribute__((address_space(3)))

__device__ __forceinline__ floatx4 mfma16(short8 a, short8 b, floatx4 c) {
  return __builtin_amdgcn_mfma_f32_16x16x32_bf16(a, b, c, 0, 0, 0);
}
__device__ __forceinline__ floatx16 mfma32(short8 a, short8 b, floatx16 c) {
  return __builtin_amdgcn_mfma_f32_32x32x16_bf16(a, b, c, 0, 0, 0);
}
// async global->LDS, 16B per lane; LDS dest = wave-uniform base + lane*16
__device__ __forceinline__ void gload16(const bf16* g, bf16* l) {
  __builtin_amdgcn_global_load_lds((const AS1 unsigned*)g, (AS3 unsigned*)l, 16, 0, 0);
}
__device__ __forceinline__ unsigned short f2b(float x) {
  bf16 t = __float2bfloat16(x);
  return *reinterpret_cast<unsigned short*>(&t);
}

// ------------- fused fp32 -> bf16 casts for all 5 inputs (one launch) -------
__global__ void cast_all_k(const float* __restrict__ x, const float* __restrict__ Wq,
                           const float* __restrict__ Wk, const float* __restrict__ Wv,
                           const float* __restrict__ Wo, bf16* __restrict__ xb,
                           bf16* __restrict__ wqkv, bf16* __restrict__ wo_b) {
  int blk = blockIdx.x;
  const float* src;
  bf16* dst;
  int off;
  if (blk < 8192)       { src = x;  dst = xb;                 off = blk; }
  else if (blk < 12288) { src = Wq; dst = wqkv;               off = blk - 8192; }
  else if (blk < 13312) { src = Wk; dst = wqkv + 2048 * 2048; off = blk - 12288; }
  else if (blk < 14336) { src = Wv; dst = wqkv + 2560 * 2048; off = blk - 13312; }
  else                  { src = Wo; dst = wo_b;               off = blk - 14336; }
  int i = (off * 256 + threadIdx.x) * 4;
  float4 v = *(const float4*)(src + i);
  bf16 t[4] = {__float2bfloat16(v.x), __float2bfloat16(v.y),
               __float2bfloat16(v.z), __float2bfloat16(v.w)};
  *(ushort4*)(dst + i) = *(const ushort4*)t;
}

// ------- GEMM C[M,N] = A[M,K] * B[N,K]^T, bf16 in, OutT out -------
template <typename OutT>
__global__ __launch_bounds__(256, 2)
void gemm_bt(const bf16* __restrict__ A, const bf16* __restrict__ B,
             OutT* __restrict__ C, int M, int N, int K) {
  __shared__ alignas(16) bf16 As[128 * 32];
  __shared__ alignas(16) bf16 Bs[128 * 32];
  const int tid = threadIdx.x;
  const int w = tid >> 6, lane = tid & 63, l16 = lane & 15, quad = lane >> 4;
  const int bm = blockIdx.x << 7, bn = blockIdx.y << 7;
  const int wm = (w & 1) << 6, wn = (w >> 1) << 6;

  const int r = tid >> 2, p = tid & 3;
  const int g0 = (p ^ ((r >> 1) & 3)) << 3;            // source group (elems)
  const int g1 = (p ^ (((r + 64) >> 1) & 3)) << 3;
  const bf16* Ag0 = A + (long)(bm + r) * K + g0;
  const bf16* Ag1 = A + (long)(bm + r + 64) * K + g1;
  const bf16* Bg0 = B + (long)(bn + r) * K + g0;
  const bf16* Bg1 = B + (long)(bn + r + 64) * K + g1;
  bf16* Asw = As + (w << 9);  // wave LDS base (64 lanes * 8 elems)
  bf16* Bsw = Bs + (w << 9);

  floatx4 acc[4][4];
#pragma unroll
  for (int i = 0; i < 4; ++i)
#pragma unroll
    for (int j = 0; j < 4; ++j) acc[i][j] = (floatx4)(0.0f);

  for (int k0 = 0; k0 < K; k0 += 32) {
    gload16(Ag0 + k0, Asw);
    gload16(Ag1 + k0, Asw + 2048);
    gload16(Bg0 + k0, Bsw);
    gload16(Bg1 + k0, Bsw + 2048);
    __syncthreads();
    short8 af[4], bfv[4];
#pragma unroll
    for (int mi = 0; mi < 4; ++mi) {
      int row = wm + (mi << 4) + l16;
      int pos = quad ^ ((row >> 1) & 3);
      af[mi] = *(const short8*)(As + row * 32 + pos * 8);
    }
#pragma unroll
    for (int ni = 0; ni < 4; ++ni) {
      int row = wn + (ni << 4) + l16;
      int pos = quad ^ ((row >> 1) & 3);
      bfv[ni] = *(const short8*)(Bs + row * 32 + pos * 8);
    }
#pragma unroll
    for (int mi = 0; mi < 4; ++mi)
#pragma unroll
      for (int ni = 0; ni < 4; ++ni)
        acc[mi][ni] = mfma16(af[mi], bfv[ni], acc[mi][ni]);
    __syncthreads();
  }

#pragma unroll
  for (int mi = 0; mi < 4; ++mi)
#pragma unroll
    for (int ni = 0; ni < 4; ++ni)
#pragma unroll
      for (int rr = 0; rr < 4; ++rr) {
        int row = bm + wm + (mi << 4) + (quad << 2) + rr;  // C/D: row=quad*4+reg
        int col = bn + wn + (ni << 4) + l16;               //      col=lane&15
        float v = acc[mi][ni][rr];
        if constexpr (sizeof(OutT) == 2)
          C[(long)row * N + col] = __float2bfloat16(v);
        else
          C[(long)row * N + col] = v;
      }
}

// ---------------- RoPE: qkv[4096][3072] -> Q[B,H,S,DH]*scale, K[B,KVH,S,DH] ----
// Q scale = 1/sqrt(128) * log2(e): attention exp(s) becomes exp2(s') directly.
__global__ void rope_k(const bf16* __restrict__ qkv, bf16* __restrict__ Q,
                       bf16* __restrict__ Kd) {
  int idx = blockIdx.x * 256 + threadIdx.x;  // 4096*20*64 threads, d-pair each
  int d = idx & 63;
  int rest = idx >> 6;
  int head = rest % 20;
  int token = rest / 20;
  int s = token & 2047;
  int b = token >> 11;
  const float C0 = 0.20762050593046439f;  // log2(10000)/64
  float i1 = (float)(d >> 1);
  float inv1 = exp2f(-i1 * C0);
  float inv2 = exp2f(-(i1 + 32.0f) * C0);
  float a1 = (float)s * inv1, a2 = (float)s * inv2;
  float s1, c1, s2, c2;
  __sincosf(a1, &s1, &c1);
  __sincosf(a2, &s2, &c2);
  if (head < 16) {
    const bf16* p = qkv + (long)token * 3072 + head * 128 + d;
    float xlo = __bfloat162float(p[0]), xhi = __bfloat162float(p[64]);
    const float sc = 0.08838834764831845f * 1.4426950408889634f;  // 1/sqrt(128)*log2e
    float olo = (xlo * c1 - xhi * s1) * sc;
    float ohi = (xhi * c2 + xlo * s2) * sc;
    bf16* q = Q + ((long)((b << 4) + head) * 2048 + s) * 128 + d;
    q[0] = __float2bfloat16(olo);
    q[64] = __float2bfloat16(ohi);
  } else {
    int kvh = head - 16;
    const bf16* p = qkv + (long)token * 3072 + 2048 + kvh * 128 + d;
    float xlo = __bfloat162float(p[0]), xhi = __bfloat162float(p[64]);
    float olo = xlo * c1 - xhi * s1;
    float ohi = xhi * c2 + xlo * s2;
    bf16* kk = Kd + ((long)((b << 2) + kvh) * 2048 + s) * 128 + d;
    kk[0] = __float2bfloat16(olo);
    kk[64] = __float2bfloat16(ohi);
  }
}

// ---------------- V transpose: qkv V cols -> Vt[B,KVH,DH,S] ----------------
__global__ void vtrans_k(const bf16* __restrict__ qkv, bf16* __restrict__ Vt) {
  __shared__ bf16 t[32][33];
  int x = threadIdx.x, y = threadIdx.y;
  int s0 = blockIdx.x << 5, d0 = blockIdx.y << 5, bkv = blockIdx.z;
  int b = bkv >> 2, kvh = bkv & 3;
  const bf16* src = qkv + (long)((b << 11) + s0) * 3072 + 2560 + kvh * 128 + d0;
#pragma unroll
  for (int yy = y; yy < 32; yy += 8) t[yy][x] = src[(long)yy * 3072 + x];
  __syncthreads();
  bf16* dst = Vt + (long)((bkv << 7) + d0) * 2048 + s0;
#pragma unroll
  for (int yy = y; yy < 32; yy += 8) dst[(long)yy * 2048 + x] = t[x][yy];
}

// ---- flash attention: 32x32 MFMA, mixed-column paired q-tiles, dbuf --------
// mask: key k valid iff k <= q + 128. Block: A = q-tile 2t, B = 2t+1 (64q
// each); wave w owns 16 qA + 16 qB as the 32 columns of ONE 32x32 MFMA
// (cols 0-15 = A, 16-31 = B) -> both paths share every kf/vf read AND every
// MFMA. Wall = nkB = 2t+4 tiles; dead-A work = 1 tile (~1%). Complementary
// t-mapping (bh<16 ? bx : 15-bx) pairs walls (2x+4)+(34-2x) per CU (blocks
// c and c+256 co-resident) -> uniform ~38 tiles/CU.
// S^T = K*Q^T (C: col=q-mixed, row=key); P=exp2(s) (pre-scaled, no max-sub);
// P C-layout -> PV A-layout via lane^32 exchange (no LDS roundtrip):
// frag(kt,kk) = [quad(2kk+h) own, quad(2kk+h) partner].
__global__ __launch_bounds__(256, 2)
void attn_k(const bf16* __restrict__ Q, const bf16* __restrict__ K,
            const bf16* __restrict__ V, bf16* __restrict__ O) {
  __shared__ alignas(16) bf16 lk[2][64 * 128];  // [key][d]   16KB x2
  __shared__ alignas(16) bf16 lv[2][128 * 64];  // [d][key]   16KB x2
  const int tid = threadIdx.x, w = tid >> 6, lane = tid & 63;
  const int cl = lane & 31, h = lane >> 5;
  const int bh = blockIdx.y, b = bh >> 4, hh = bh & 15, kvh = hh >> 2;
  const int t = (bh < 16) ? blockIdx.x : (15 - blockIdx.x);
  const int qa0 = (2 * t) << 6, qb0 = (2 * t + 1) << 6;
  int nkt = 2 * t + 4;
  const int nkB = nkt < 32 ? nkt : 32;
  const int jmA = 2 * t + 2, jmB = 2 * t + 3;   // straddle tiles (A then B)
  const bf16* Qp = Q + (long)bh * 2048 * 128;
  const bf16* Kp = K + (long)((b << 2) + kvh) * 2048 * 128;
  const bf16* Vp = V + (long)((b << 2) + kvh) * 128 * 2048;
  const int wq = w << 4;
  // this lane's query (column): cols<16 -> path A, else path B
  const int qpos = (cl < 16) ? (qa0 + wq + cl) : (qb0 + wq + (cl - 16));
  const int jm_lane = (cl < 16) ? jmA : jmB;

  short8 qf[8];  // Q B-frags: n=q-mixed(lane&31), k=(lane>>5)*8+j, ks over DH/16
#pragma unroll
  for (int ks = 0; ks < 8; ++ks)
    qf[ks] = *(const short8*)(Qp + (long)qpos * 128 + ks * 16 + h * 8);

  floatx16 o[4];  // O: rows=q-mixed, cols=d (dt*32 + cl)
#pragma unroll
  for (int dt = 0; dt < 4; ++dt) o[dt] = (floatx16)(0.0f);
  float lsum = 0.0f;  // l for column qpos (rows split across lane^32 pair)

  // stage 64-key K/V tile j into buffer bufi (8 gload16 per thread)
  auto stage = [&](int j, int bufi) {
    const int k0 = j << 6;
    bf16* lkb = &lk[bufi][0];
    bf16* lvb = &lv[bufi][0];
#pragma unroll
    for (int i = 0; i < 4; ++i) {  // K [64][128]
      int c = i * 256 + tid;
      int row = c >> 4, pos = c & 15;
      int grp = (pos & 8) | ((pos & 7) ^ (row & 7));
      gload16(Kp + (long)(k0 + row) * 128 + grp * 8, lkb + (i * 256 + (w << 6)) * 8);
    }
#pragma unroll
    for (int i = 0; i < 4; ++i) {  // V [128 d][64 k]
      int c = i * 256 + tid;
      int row = c >> 3, grp = (c & 7) ^ (row & 7);
      gload16(Vp + (long)row * 2048 + k0 + grp * 8, lvb + (i * 256 + (w << 6)) * 8);
    }
  };

  stage(0, 0);
  __syncthreads();  // vmcnt(0) drain -> buf0 ready
  for (int j = 0; j < nkB; ++j) {
    if (j + 1 < nkB) stage(j + 1, (j + 1) & 1);  // prefetch overlaps compute
    const int k0 = j << 6;
    const bf16* lkb = &lk[j & 1][0];
    const bf16* lvb = &lv[j & 1][0];

    floatx16 s[2];  // S^T for key-row-tiles kt: col=q-mixed, row=key
    s[0] = (floatx16)(0.0f);
    s[1] = (floatx16)(0.0f);
#pragma unroll
    for (int ks = 0; ks < 8; ++ks) {
      int g = 2 * ks + h;
#pragma unroll
      for (int kt = 0; kt < 2; ++kt) {
        int row = (kt << 5) + cl;
        int pos = (g & 8) | ((g & 7) ^ (row & 7));
        short8 kf = *(const short8*)(lkb + row * 128 + pos * 8);
        s[kt] = mfma32(kf, qf[ks], s[kt]);
      }
    }

    // mask (straddle for A at jmA, B at jmB; kill dead-A for j>jmA)
    if (j >= jmA) {
      int qlim = (j < jm_lane) ? 0x7fffffff : ((j == jm_lane) ? (qpos + 128) : -1);
#pragma unroll
      for (int kt = 0; kt < 2; ++kt)
#pragma unroll
        for (int r = 0; r < 16; ++r) {
          int key = k0 + (kt << 5) + (r & 3) + ((r >> 2) << 3) + (h << 2);
          if (key > qlim) s[kt][r] = -1e30f;
        }
    }

    // P = exp2(s); accumulate partial l (column sum over this lane's rows)
#pragma unroll
    for (int kt = 0; kt < 2; ++kt)
#pragma unroll
      for (int r = 0; r < 16; ++r) {
        float p = exp2f(s[kt][r]);
        lsum += p;
        s[kt][r] = p;
      }

    // transform C-layout P -> A-layout frags via lane^32 exchange, then PV
#pragma unroll
    for (int kt = 0; kt < 2; ++kt) {
#pragma unroll
      for (int kk = 0; kk < 2; ++kk) {
        // send partner's needed quad (2kk + partner_h), receive quad (2kk+h)
        float sd0 = h ? s[kt][8 * kk + 0] : s[kt][8 * kk + 4];
        float sd1 = h ? s[kt][8 * kk + 1] : s[kt][8 * kk + 5];
        float sd2 = h ? s[kt][8 * kk + 2] : s[kt][8 * kk + 6];
        float sd3 = h ? s[kt][8 * kk + 3] : s[kt][8 * kk + 7];
        float rc0 = __shfl_xor(sd0, 32);
        float rc1 = __shfl_xor(sd1, 32);
        float rc2 = __shfl_xor(sd2, 32);
        float rc3 = __shfl_xor(sd3, 32);
        float lo0 = h ? rc0 : s[kt][8 * kk + 0];
        float lo1 = h ? rc1 : s[kt][8 * kk + 1];
        float lo2 = h ? rc2 : s[kt][8 * kk + 2];
        float lo3 = h ? rc3 : s[kt][8 * kk + 3];
        float hi0 = h ? s[kt][8 * kk + 4] : rc0;
        float hi1 = h ? s[kt][8 * kk + 5] : rc1;
        float hi2 = h ? s[kt][8 * kk + 6] : rc2;
        float hi3 = h ? s[kt][8 * kk + 7] : rc3;
        union { short8 v; unsigned short u[8]; } pf;
        pf.u[0] = f2b(lo0); pf.u[1] = f2b(lo1); pf.u[2] = f2b(lo2); pf.u[3] = f2b(lo3);
        pf.u[4] = f2b(hi0); pf.u[5] = f2b(hi1); pf.u[6] = f2b(hi2); pf.u[7] = f2b(hi3);
        int g = (kt << 2) + (kk << 1) + h;  // 8-key group in lv
#pragma unroll
        for (int dt = 0; dt < 4; ++dt) {
          int vrow = (dt << 5) + cl;
          int vpos = g ^ (vrow & 7);
          short8 vf = *(const short8*)(lvb + vrow * 64 + (vpos << 3));
          o[dt] = mfma32(pf.v, vf, o[dt]);
        }
      }
    }
    __syncthreads();  // drains prefetch (had full compute phase in flight)
  }

  // l: combine the two row-halves (lane^32), invert, redistribute to rows
  lsum += __shfl_xor(lsum, 32);
  float li = 1.0f / lsum;
  bf16* Ob = O + ((long)(b << 11)) * 2048 + (hh << 7) + cl;
#pragma unroll
  for (int r = 0; r < 16; ++r) {
    int m = (r & 3) + ((r >> 2) << 3) + (h << 2);  // q-mixed row index
    float rl = __shfl(li, m);                      // lane m holds col m's l
    long row = (m < 16) ? (qa0 + wq + m) : (qb0 + wq + (m - 16));
#pragma unroll
    for (int dt = 0; dt < 4; ++dt)
      Ob[row * 2048 + dt * 32] = __float2bfloat16(o[dt][r] * rl);
  }
}

extern "C" void kernel_launch(void* const* d_in, const int* in_sizes, int n_in,
                              void* d_out, int out_size, void* d_ws, size_t ws_size,
                              hipStream_t stream) {
  (void)in_sizes; (void)n_in; (void)out_size; (void)ws_size;
  const float* x  = (const float*)d_in[0];
  const float* Wq = (const float*)d_in[1];
  const float* Wk = (const float*)d_in[2];
  const float* Wv = (const float*)d_in[3];
  const float* Wo = (const float*)d_in[4];
  char* ws = (char*)d_ws;
  // ws layout (bytes): xb 16.7M | wqkv 12.6M | wo_b 8.4M | qkv 25.2M | Q 16.8M | K 4.2M | Vt 4.2M
  bf16* xb   = (bf16*)(ws);                 // also reused as Ob after gemm1
  bf16* wqkv = (bf16*)(ws + 16777216);
  bf16* wo_b = (bf16*)(ws + 29360128);
  bf16* qkv  = (bf16*)(ws + 37748736);
  bf16* Qr   = (bf16*)(ws + 62914560);
  bf16* Kr   = (bf16*)(ws + 79691776);
  bf16* Vt   = (bf16*)(ws + 83886080);
  bf16* Ob   = xb;  // x dead after QKV GEMM
  float* out = (float*)d_out;

  cast_all_k<<<18432, 256, 0, stream>>>(x, Wq, Wk, Wv, Wo, xb, wqkv, wo_b);

  gemm_bt<bf16><<<dim3(32, 24), 256, 0, stream>>>(xb, wqkv, qkv, 4096, 3072, 2048);
  rope_k<<<20480, 256, 0, stream>>>(qkv, Qr, Kr);
  vtrans_k<<<dim3(64, 4, 8), dim3(32, 8), 0, stream>>>(qkv, Vt);
  attn_k<<<dim3(16, 32), 256, 0, stream>>>(Qr, Kr, Vt, Ob);
  gemm_bt<float><<<dim3(32, 16), 256, 0, stream>>>(Ob, wo_b, out, 4096, 2048, 2048);
}